// Round 17
// baseline (2107.955 us; speedup 1.0000x reference)
//
#include <hip/hip_runtime.h>
#include <cstdint>
#include <cstddef>

#define SEQT  512
#define HID   1024
#define HSTR  1088   // h_lds row stride in shorts (2176 B)
#define RING  32     // xg ring depth
#define FSTR  32     // flag stride in u32 (128 B)
#define RS    ((size_t)RING * 16 * 3072)   // ring shorts per half-layer

typedef __attribute__((ext_vector_type(8))) short bf16x8;
typedef __attribute__((ext_vector_type(8))) unsigned short u16x8;
typedef __attribute__((ext_vector_type(4))) float f32x4;

__device__ __forceinline__ float sigm(float x){ return 1.0f/(1.0f+expf(-x)); }
__device__ __forceinline__ float b2f(unsigned short s){ return __uint_as_float(((uint32_t)s)<<16); }
__device__ __forceinline__ unsigned short f2b(float f){
    uint32_t u=__float_as_uint(f);
    return (unsigned short)((u + 0x7FFFu + ((u>>16)&1u))>>16);
}

// ---------------------------------------------------------------------------
// MFMA GEMM (proven since R3). ASRC: 1=f32 reg-staged, 2=bf16 + (1+gate) fuse.
// BSRC: 1=f32 reg-staged. MODE: 0=f32+bias, 1=bf16 tanh(+bias+ctx).
// ---------------------------------------------------------------------------
template<int ASRC, int BSRC, int MODE>
__global__ __launch_bounds__(256) void mfma_gemm(
    const void* __restrict__ Av, const void* __restrict__ Bv,
    const float* __restrict__ bias, const float* __restrict__ ctx,
    const float* __restrict__ gate, void* __restrict__ Cv,
    int N, int K)
{
    __shared__ __align__(16) unsigned short As[128*64];
    __shared__ __align__(16) unsigned short Bs[128*64];
    const int tid = threadIdx.x;
    const int lane = tid & 63;
    const int w = tid >> 6;
    const int wm = w & 1, wn = w >> 1;
    const int m0 = blockIdx.y * 128, n0 = blockIdx.x * 128;

    f32x4 acc[4][4];
#pragma unroll
    for (int i = 0; i < 4; i++)
#pragma unroll
        for (int j = 0; j < 4; j++) acc[i][j] = (f32x4){0.f,0.f,0.f,0.f};

    for (int kt = 0; kt < K; kt += 64) {
        __syncthreads();
        if (ASRC == 1) {
            const float* Af = (const float*)Av;
#pragma unroll
            for (int p = 0; p < 4; p++) {
                const int q = p*256 + tid, row = q>>3, kc = q&7;
                const float* src = Af + (size_t)(m0+row)*K + kt + kc*8;
                float4 u = *(const float4*)src, v = *(const float4*)(src+4);
                __align__(16) unsigned short tmp[8] =
                    {f2b(u.x),f2b(u.y),f2b(u.z),f2b(u.w),f2b(v.x),f2b(v.y),f2b(v.z),f2b(v.w)};
                *(bf16x8*)&As[row*64 + kc*8] = *(const bf16x8*)tmp;
            }
        } else {
            const unsigned short* Ab = (const unsigned short*)Av;
#pragma unroll
            for (int p = 0; p < 4; p++) {
                const int q = p*256 + tid, row = q>>3, kc = q&7;
                const int b = (m0+row) >> 9;
                u16x8 hv = *(const u16x8*)(Ab + (size_t)(m0+row)*K + kt + kc*8);
                const float* gp = gate + (size_t)b*HID + kt + kc*8;
                float4 g0 = *(const float4*)gp, g1 = *(const float4*)(gp+4);
                const float gg[8] = {g0.x,g0.y,g0.z,g0.w,g1.x,g1.y,g1.z,g1.w};
                __align__(16) unsigned short tmp[8];
#pragma unroll
                for (int e = 0; e < 8; e++)
                    tmp[e] = f2b(b2f(hv[e]) * (1.0f + gg[e]));
                *(bf16x8*)&As[row*64 + kc*8] = *(const bf16x8*)tmp;
            }
        }
        {
            const float* Bf = (const float*)Bv;
#pragma unroll
            for (int p = 0; p < 4; p++) {
                const int q = p*256 + tid, row = q>>3, kc = q&7;
                const float* src = Bf + (size_t)(n0+row)*K + kt + kc*8;
                float4 u = *(const float4*)src, v = *(const float4*)(src+4);
                __align__(16) unsigned short tmp[8] =
                    {f2b(u.x),f2b(u.y),f2b(u.z),f2b(u.w),f2b(v.x),f2b(v.y),f2b(v.z),f2b(v.w)};
                *(bf16x8*)&Bs[row*64 + kc*8] = *(const bf16x8*)tmp;
            }
        }
        __syncthreads();
#pragma unroll
        for (int kg = 0; kg < 2; kg++) {
            bf16x8 af[4], bfr[4];
#pragma unroll
            for (int mi = 0; mi < 4; mi++)
                af[mi] = *(const bf16x8*)&As[(wm*64+mi*16+(lane&15))*64 + kg*32 + (lane>>4)*8];
#pragma unroll
            for (int ni = 0; ni < 4; ni++)
                bfr[ni] = *(const bf16x8*)&Bs[(wn*64+ni*16+(lane&15))*64 + kg*32 + (lane>>4)*8];
#pragma unroll
            for (int mi = 0; mi < 4; mi++)
#pragma unroll
                for (int ni = 0; ni < 4; ni++)
                    acc[mi][ni] = __builtin_amdgcn_mfma_f32_16x16x32_bf16(
                        af[mi], bfr[ni], acc[mi][ni], 0, 0, 0);
        }
    }

    const int cl = lane & 15, rg = lane >> 4;
    const int bct = m0 >> 9;
#pragma unroll
    for (int mi = 0; mi < 4; mi++) {
        const int rowb = m0 + wm*64 + mi*16 + rg*4;
#pragma unroll
        for (int ni = 0; ni < 4; ni++) {
            const int col = n0 + wn*64 + ni*16 + cl;
            const float bv = bias[col];
            const float cv = (MODE==1) ? ctx[(size_t)bct*HID + col] : 0.0f;
#pragma unroll
            for (int r = 0; r < 4; r++) {
                float val = acc[mi][ni][r] + bv;
                if (MODE==1) val = tanhf(val + cv);
                const size_t off = (size_t)(rowb+r)*N + col;
                if (MODE==0) ((float*)Cv)[off] = val;
                else ((unsigned short*)Cv)[off] = f2b(val);
            }
        }
    }
}

// ---------------------------------------------------------------------------
__global__ __launch_bounds__(256) void gate_kernel(
    const float* __restrict__ ctx, const float* __restrict__ Wg,
    const float* __restrict__ bg, float* __restrict__ gate)
{
    const int j = blockIdx.x * 256 + threadIdx.x;
    const int b = blockIdx.y;
    const float4* cp = (const float4*)(ctx + (size_t)b * HID);
    const float4* wp = (const float4*)(Wg + (size_t)j * HID);
    float acc = 0.0f;
#pragma unroll 4
    for (int k = 0; k < HID / 4; k++) {
        float4 c = cp[k], w = wp[k];
        acc += c.x * w.x + c.y * w.y + c.z * w.z + c.w * w.w;
    }
    gate[(size_t)b * HID + j] = sigm(acc + bg[j]);
}

// agent-scope (LLC) polls — proven semantics (R4-R15)
__device__ __forceinline__ void poll_ge(const unsigned int* p, unsigned int tgt)
{
    while (__hip_atomic_load(p, __ATOMIC_RELAXED, __HIP_MEMORY_SCOPE_AGENT) < tgt)
        __builtin_amdgcn_s_sleep(2);
}
__device__ __forceinline__ void poll_ge_fast(const unsigned int* p, unsigned int tgt)
{
    while (__hip_atomic_load(p, __ATOMIC_RELAXED, __HIP_MEMORY_SCOPE_AGENT) < tgt) {}
}

// ---------------------------------------------------------------------------
// XCD-local 4-stage GRU pipe — R15 topology (proven 1.81ms), agent flags ONLY
// (R16's sc0 L2 flags deadlocked -> reverted). R17 deltas:
//  * flag store by tid64 (w1): w0's poll loads never wait a pending store ack
//  * redundant kh-group staging: each wave stages all 16 rows of ITS K-half
//    (3x redundant, same data) -> wave-local vmcnt(0) replaces a barrier
//  * busy-poll for R peer flags (no sleep quantization)
// xcd0/1=R0  xcd2/3=P1  xcd4/5=R1  xcd6/7=P0 (half = xcd&1), rank via XCC_ID.
// ---------------------------------------------------------------------------
__global__ __launch_bounds__(384, 1) void gru_pipe(
    const float* __restrict__ Wih0, const float* __restrict__ Whh0,
    const float* __restrict__ bih0, const float* __restrict__ bhh0,
    const float* __restrict__ Wih1, const float* __restrict__ Whh1,
    const float* __restrict__ bih1, const float* __restrict__ bhh1,
    const unsigned short* __restrict__ mixed,
    unsigned short* __restrict__ h1,
    unsigned short* __restrict__ h2,
    unsigned short* __restrict__ xgs,           // 4 x [RING][16][3072]
    unsigned int* __restrict__ flags)           // 8 sets x 32 x FSTR + counters
{
    __shared__ __align__(16) unsigned short h_lds[40*HSTR];  // >80KB: 1 block/CU
    __shared__ float sc[192*17];
    __shared__ int s_xcd, s_rank;

    const int tid = threadIdx.x;
    const int lane = tid & 63;
    const int w = tid >> 6;
    const int cl = lane & 15, kq = lane >> 4;

    if (tid == 0) {
        unsigned x;
        asm volatile("s_getreg_b32 %0, hwreg(HW_REG_XCC_ID, 0, 32)" : "=s"(x));
        x &= 7u;
        s_xcd = (int)x;
        s_rank = (int)atomicAdd(&flags[8*32*FSTR + x*16], 1u);
    }
    __syncthreads();
    const int xcd = s_xcd;
    const int rb  = s_rank & 31;
    const int half = xcd & 1;
    const int kind = xcd >> 1;            // 0=R0 1=P1 2=R1 3=P0
    const int col0 = rb * 32;
    const int bb   = half * 16;

    unsigned int* fsetb = flags;          // set i at flags + i*32*FSTR (all agent)

    // ---- weights -> registers: 2 N-blocks x 16 k-groups (K-half kh) -------
    const int g = w >> 1, kh = w & 1;
    const float* Wsrc = (kind==0) ? Whh0 : (kind==1) ? Wih1
                      : (kind==2) ? Whh1 : Wih0;
    bf16x8 wreg[32];
#pragma unroll
    for (int nb = 0; nb < 2; nb++) {
        const float* wr = Wsrc + (size_t)(g*1024 + col0 + nb*16 + cl)*1024 + kh*512 + kq*8;
#pragma unroll
        for (int kg = 0; kg < 16; kg++) {
            float4 u = *(const float4*)(wr + (size_t)kg*32);
            float4 v = *(const float4*)(wr + (size_t)kg*32 + 4);
            __align__(16) unsigned short tmp[8] =
                {f2b(u.x),f2b(u.y),f2b(u.z),f2b(u.w),f2b(v.x),f2b(v.y),f2b(v.z),f2b(v.w)};
            wreg[nb*16 + kg] = *(const bf16x8*)tmp;
        }
    }
#pragma unroll
    for (int i = 0; i < 32; i++) asm volatile("" : "+v"(wreg[i]));

    const int rot = (cl & 7) << 4;
    const char* hbytes = (const char*)h_lds;

    unsigned short* ring = xgs + (size_t)((kind==0 || kind==3) ? half : 2+half) * RS;

    if (kind == 0 || kind == 2) {
        // ====================== R stage (recurrence) ======================
        unsigned short* hdst = (kind == 0) ? h1 : h2;
        const float* bih = (kind == 0) ? bih0 : bih1;
        const float* bhh = (kind == 0) ? bhh0 : bhh1;
        const unsigned int* peers = fsetb + xcd*32*FSTR;
        const unsigned int* prod  = fsetb + ((kind==0) ? (6+half) : (2+half))*32*FSTR;
        unsigned int* myflag = (unsigned int*)(peers + rb*FSTR);

        const int fb = tid >> 4;
        const int fj = (tid & 15) * 2;
        float hp0 = 0.f, hp1 = 0.f;
        float br0=0,br1=0,bz0=0,bz1=0,bni0=0,bni1=0,bnh0=0,bnh1=0;
        if (tid < 256) {
            const int jc = col0 + fj;
            br0 = bih[jc]         + bhh[jc];
            br1 = bih[jc+1]       + bhh[jc+1];
            bz0 = bih[HID+jc]     + bhh[HID+jc];
            bz1 = bih[HID+jc+1]   + bhh[HID+jc+1];
            bni0 = bih[2*HID+jc];    bni1 = bih[2*HID+jc+1];
            bnh0 = bhh[2*HID+jc];    bnh1 = bhh[2*HID+jc+1];
        }

        for (int t = 0; t < SEQT; t++) {
            if (w == 0 && lane < 32 && t > 0)
                poll_ge_fast(&peers[lane*FSTR], (unsigned)t);   // busy-poll
            if (w == 2 && lane == 0)
                poll_ge(&prod[rb*FSTR], (unsigned)(t+1));       // column partner
            __syncthreads();

            // xg ring reads (agent atomics) — issue early, complete under stage
            uint32_t xr2=0, xz2=0, xn2=0;
            if (tid < 256) {
                const unsigned short* xp = ring + ((size_t)(t & (RING-1))*16 + fb)*3072;
                xr2 = __hip_atomic_load((const unsigned int*)(xp + col0 + fj),
                                        __ATOMIC_RELAXED, __HIP_MEMORY_SCOPE_AGENT);
                xz2 = __hip_atomic_load((const unsigned int*)(xp + 1024 + col0 + fj),
                                        __ATOMIC_RELAXED, __HIP_MEMORY_SCOPE_AGENT);
                xn2 = __hip_atomic_load((const unsigned int*)(xp + 2048 + col0 + fj),
                                        __ATOMIC_RELAXED, __HIP_MEMORY_SCOPE_AGENT);
            }
            if (t > 0) {
                // redundant per-wave staging: each wave stages ALL 16 rows of
                // its OWN kh half -> reads only bytes it staged itself, so a
                // wave-local vmcnt(0) suffices (no barrier).
#pragma unroll
                for (int r = 0; r < 16; r++) {
                    const char* src = (const char*)hdst
                        + (((size_t)(bb + r)*SEQT + (t-1))*HID)*2
                        + kh*1024 + ((lane*16) ^ ((r & 7) << 4));
                    __builtin_amdgcn_global_load_lds(
                        (const __attribute__((address_space(1))) void*)src,
                        (__attribute__((address_space(3))) void*)
                            ((char*)h_lds + r*2176 + kh*1024),
                        16, 0, 0);
                }
            }
            asm volatile("s_waitcnt vmcnt(0)" ::: "memory");

            f32x4 A00={0.f,0.f,0.f,0.f}, A01=A00, A10=A00, A11=A00;
            if (t > 0) {
#pragma unroll
                for (int kg = 0; kg < 16; kg++) {
                    bf16x8 hv = *(const bf16x8*)(hbytes + cl*2176 +
                        ((kh*1024 + kg*64 + kq*16) ^ rot));
                    if (kg & 1) {
                        A01 = __builtin_amdgcn_mfma_f32_16x16x32_bf16(hv, wreg[kg],    A01, 0,0,0);
                        A11 = __builtin_amdgcn_mfma_f32_16x16x32_bf16(hv, wreg[16+kg], A11, 0,0,0);
                    } else {
                        A00 = __builtin_amdgcn_mfma_f32_16x16x32_bf16(hv, wreg[kg],    A00, 0,0,0);
                        A10 = __builtin_amdgcn_mfma_f32_16x16x32_bf16(hv, wreg[16+kg], A10, 0,0,0);
                    }
                }
            }
            f32x4 av0 = A00 + A01, av1 = A10 + A11;
#pragma unroll
            for (int r = 0; r < 4; r++) {
                sc[((g*4 + kh*2 + 0)*16 + kq*4 + r)*17 + cl] = av0[r];
                sc[((g*4 + kh*2 + 1)*16 + kq*4 + r)*17 + cl] = av1[r];
            }
            __syncthreads();

            if (tid < 256) {
                const int c0 = fj, nb = c0 >> 4, cc = c0 & 15;
                const float sr0 = sc[((0*4+nb)*16+fb)*17+cc]   + sc[((0*4+2+nb)*16+fb)*17+cc];
                const float sr1 = sc[((0*4+nb)*16+fb)*17+cc+1] + sc[((0*4+2+nb)*16+fb)*17+cc+1];
                const float sz0 = sc[((1*4+nb)*16+fb)*17+cc]   + sc[((1*4+2+nb)*16+fb)*17+cc];
                const float sz1 = sc[((1*4+nb)*16+fb)*17+cc+1] + sc[((1*4+2+nb)*16+fb)*17+cc+1];
                const float sn0 = sc[((2*4+nb)*16+fb)*17+cc]   + sc[((2*4+2+nb)*16+fb)*17+cc];
                const float sn1 = sc[((2*4+nb)*16+fb)*17+cc+1] + sc[((2*4+2+nb)*16+fb)*17+cc+1];
                const float r0 = sigm(b2f((unsigned short)(xr2 & 0xFFFF)) + sr0 + br0);
                const float r1 = sigm(b2f((unsigned short)(xr2 >> 16))    + sr1 + br1);
                const float z0 = sigm(b2f((unsigned short)(xz2 & 0xFFFF)) + sz0 + bz0);
                const float z1 = sigm(b2f((unsigned short)(xz2 >> 16))    + sz1 + bz1);
                const float n0 = tanhf(b2f((unsigned short)(xn2 & 0xFFFF)) + bni0 + r0*(sn0 + bnh0));
                const float n1 = tanhf(b2f((unsigned short)(xn2 >> 16))    + bni1 + r1*(sn1 + bnh1));
                const float h0 = (1.0f - z0)*n0 + z0*hp0;
                const float h1v = (1.0f - z1)*n1 + z1*hp1;
                hp0 = h0; hp1 = h1v;
                const uint32_t hv = (uint32_t)f2b(h0) | ((uint32_t)f2b(h1v) << 16);
                uint32_t* dst = (uint32_t*)(hdst + ((size_t)(bb+fb)*SEQT + t)*HID + col0 + fj);
                __hip_atomic_store(dst, hv, __ATOMIC_RELAXED, __HIP_MEMORY_SCOPE_AGENT);
            }
            asm volatile("s_waitcnt vmcnt(0)" ::: "memory");    // h stores acked (LLC)
            __syncthreads();
            if (tid == 64)                                      // w1: w0 polls clean
                __hip_atomic_store(myflag, (unsigned)(t+1),
                                   __ATOMIC_RELAXED, __HIP_MEMORY_SCOPE_AGENT);
        }
    } else {
        // ====================== P stage (feed-forward) ====================
        const unsigned short* src_base = (kind == 3) ? mixed : h1;
        const unsigned int* waitin = (kind == 1) ? (fsetb + (0+half)*32*FSTR) : nullptr;
        const unsigned int* bp = fsetb + ((kind==3) ? (0+half) : (4+half))*32*FSTR;
        unsigned int* myflag = fsetb + xcd*32*FSTR + rb*FSTR;

        for (int t = 0; t < SEQT; t++) {
            if (w == 0 && lane < 32 && waitin)
                poll_ge(&waitin[lane*FSTR], (unsigned)(t+1));
            if (w == 2 && lane < 32 && t >= RING && (t & 7) == 0)
                poll_ge(&bp[lane*FSTR], (unsigned)(t - 24));
            __syncthreads();

            // redundant per-wave staging of src[t] (own kh half, 16 rows)
#pragma unroll
            for (int r = 0; r < 16; r++) {
                const char* src = (const char*)src_base
                    + (((size_t)(bb + r)*SEQT + t)*HID)*2
                    + kh*1024 + ((lane*16) ^ ((r & 7) << 4));
                __builtin_amdgcn_global_load_lds(
                    (const __attribute__((address_space(1))) void*)src,
                    (__attribute__((address_space(3))) void*)
                        ((char*)h_lds + r*2176 + kh*1024),
                    16, 0, 0);
            }
            asm volatile("s_waitcnt vmcnt(0)" ::: "memory");

            f32x4 A00={0.f,0.f,0.f,0.f}, A01=A00, A10=A00, A11=A00;
#pragma unroll
            for (int kg = 0; kg < 16; kg++) {
                bf16x8 hv = *(const bf16x8*)(hbytes + cl*2176 +
                    ((kh*1024 + kg*64 + kq*16) ^ rot));
                if (kg & 1) {
                    A01 = __builtin_amdgcn_mfma_f32_16x16x32_bf16(hv, wreg[kg],    A01, 0,0,0);
                    A11 = __builtin_amdgcn_mfma_f32_16x16x32_bf16(hv, wreg[16+kg], A11, 0,0,0);
                } else {
                    A00 = __builtin_amdgcn_mfma_f32_16x16x32_bf16(hv, wreg[kg],    A00, 0,0,0);
                    A10 = __builtin_amdgcn_mfma_f32_16x16x32_bf16(hv, wreg[16+kg], A10, 0,0,0);
                }
            }
            f32x4 av0 = A00 + A01, av1 = A10 + A11;
#pragma unroll
            for (int r = 0; r < 4; r++) {
                sc[((g*4 + kh*2 + 0)*16 + kq*4 + r)*17 + cl] = av0[r];
                sc[((g*4 + kh*2 + 1)*16 + kq*4 + r)*17 + cl] = av1[r];
            }
            __syncthreads();

            if (tid < 192) {
                const int fb = tid / 12, gi = tid % 12;
                const int gg = gi >> 2, c8 = (gi & 3) * 8;
                unsigned short v[8];
#pragma unroll
                for (int k = 0; k < 8; k++) {
                    const int c = c8 + k, nb = c >> 4, cc = c & 15;
                    v[k] = f2b(sc[((gg*4+nb)*16+fb)*17+cc] + sc[((gg*4+2+nb)*16+fb)*17+cc]);
                }
                const uint64_t lo = (uint64_t)v[0] | ((uint64_t)v[1]<<16)
                                  | ((uint64_t)v[2]<<32) | ((uint64_t)v[3]<<48);
                const uint64_t hi = (uint64_t)v[4] | ((uint64_t)v[5]<<16)
                                  | ((uint64_t)v[6]<<32) | ((uint64_t)v[7]<<48);
                uint64_t* dst = (uint64_t*)(ring + ((size_t)(t & (RING-1))*16 + fb)*3072
                                            + gg*1024 + col0 + c8);
                __hip_atomic_store(dst,   lo, __ATOMIC_RELAXED, __HIP_MEMORY_SCOPE_AGENT);
                __hip_atomic_store(dst+1, hi, __ATOMIC_RELAXED, __HIP_MEMORY_SCOPE_AGENT);
            }
            asm volatile("s_waitcnt vmcnt(0)" ::: "memory");
            __syncthreads();
            if (tid == 64)
                __hip_atomic_store(myflag, (unsigned)(t+1),
                                   __ATOMIC_RELAXED, __HIP_MEMORY_SCOPE_AGENT);
        }
    }
}

// ---------------------------------------------------------------------------
__global__ __launch_bounds__(256) void diag_kernel(float* __restrict__ out,
                                                   int n, float code)
{
    for (int i = blockIdx.x * 256 + threadIdx.x; i < n; i += gridDim.x * 256)
        out[i] = (i == 0) ? code : 0.0f;
}

// ---------------------------------------------------------------------------
extern "C" void kernel_launch(void* const* d_in, const int* in_sizes, int n_in,
                              void* d_out, int out_size, void* d_ws, size_t ws_size,
                              hipStream_t stream)
{
    const float* x      = (const float*)d_in[0];
    const float* ctx    = (const float*)d_in[1];
    const float* W_in   = (const float*)d_in[2];
    const float* b_in   = (const float*)d_in[3];
    const float* Wih0   = (const float*)d_in[4];
    const float* Whh0   = (const float*)d_in[5];
    const float* bih0   = (const float*)d_in[6];
    const float* bhh0   = (const float*)d_in[7];
    const float* Wih1   = (const float*)d_in[8];
    const float* Whh1   = (const float*)d_in[9];
    const float* bih1   = (const float*)d_in[10];
    const float* bhh1   = (const float*)d_in[11];
    const float* W_out  = (const float*)d_in[12];
    const float* b_out  = (const float*)d_in[13];
    const float* W_gate = (const float*)d_in[14];
    const float* b_gate = (const float*)d_in[15];
    float* out = (float*)d_out;

    const size_t MX  = (size_t)16384 * 1024 * 2;        // 32 MiB each
    const size_t XGS = (size_t)4 * RS * 2;              // 12 MiB
    const size_t GT  = (size_t)32 * 1024 * 4;
    const size_t FL  = (size_t)(8*32*FSTR + 256) * 4;   // sets + counters
    const size_t need = 3*MX + XGS + GT + FL;

    if (ws_size < need) {
        diag_kernel<<<2048, 256, 0, stream>>>(out, out_size, (float)(ws_size >> 20));
        return;
    }

    char* ws = (char*)d_ws;
    unsigned short* mixed = (unsigned short*)ws;
    unsigned short* h1    = (unsigned short*)(ws + MX);
    unsigned short* h2    = (unsigned short*)(ws + 2*MX);
    unsigned short* xgs   = (unsigned short*)(ws + 3*MX);
    float*          gate  = (float*)(ws + 3*MX + XGS);
    unsigned int*   flags = (unsigned int*)(ws + 3*MX + XGS + GT);

    hipMemsetAsync(flags, 0, FL, stream);
    gate_kernel<<<dim3(4, 32), 256, 0, stream>>>(ctx, W_gate, b_gate, gate);

    // mixed = tanh(x @ W_in^T + b_in + ctx[b]) -> bf16
    mfma_gemm<1, 1, 1><<<dim3(8, 128), 256, 0, stream>>>(
        x, W_in, b_in, ctx, nullptr, mixed, 1024, 1024);

    // XCD-local 4-stage pipelined GRU section (agent flags, proven semantics)
    gru_pipe<<<256, 384, 0, stream>>>(
        Wih0, Whh0, bih0, bhh0, Wih1, Whh1, bih1, bhh1,
        mixed, h1, h2, xgs, flags);

    // out = (h2 * (1+gate)) @ W_out^T + b_out -> f32
    mfma_gemm<2, 1, 0><<<dim3(8, 128), 256, 0, stream>>>(
        h2, W_out, b_out, nullptr, gate, out, 1024, 1024);
}